// Round 4
// baseline (39.429 us; speedup 1.0000x reference)
//
#include <hip/hip_runtime.h>

// ChannelRoll: out[row, c] = x[row, (c + m[row]) & 255], C = 256 fp32.
// One wave = one row (per iteration). Coalesced 16B read+write; roll done
// in-register via 4 shuffles + uniform slot rotation (m = 4q + r, wave-uniform).
// R4: grid-stride over rows with 2x manual unroll (load ILP across rows) and
// nontemporal load/store (streaming traffic, zero reuse -> bypass cache alloc).
// Uses native clang vector type (ext_vector_type) — HIP's float4 class is
// rejected by the nontemporal builtins.

typedef float vfloat4 __attribute__((ext_vector_type(4)));

__device__ __forceinline__ vfloat4 roll_row(vfloat4 v, int m, int lane) {
    int q = m >> 2;
    int r = m & 3;
    float t0 = __shfl(v.x, (lane + q + (0 < r ? 1 : 0)) & 63, 64);
    float t1 = __shfl(v.y, (lane + q + (1 < r ? 1 : 0)) & 63, 64);
    float t2 = __shfl(v.z, (lane + q + (2 < r ? 1 : 0)) & 63, 64);
    float t3 = __shfl(v.w, (lane + q + (3 < r ? 1 : 0)) & 63, 64);
    vfloat4 o;
    switch (r) {
        case 0:  o.x = t0; o.y = t1; o.z = t2; o.w = t3; break;
        case 1:  o.x = t1; o.y = t2; o.z = t3; o.w = t0; break;
        case 2:  o.x = t2; o.y = t3; o.z = t0; o.w = t1; break;
        default: o.x = t3; o.y = t0; o.z = t1; o.w = t2; break;
    }
    return o;
}

__global__ __launch_bounds__(256) void ChannelRoll_kernel(
    const vfloat4* __restrict__ x4,
    const int*     __restrict__ shift,
    vfloat4*       __restrict__ out4,
    int nrows)
{
    int lane   = threadIdx.x & 63;
    int wave   = (blockIdx.x * blockDim.x + threadIdx.x) >> 6;
    int nwaves = (gridDim.x * blockDim.x) >> 6;

    int row = wave;
    // 2x unrolled: two independent rows in flight -> loads overlap shuffles.
    for (; row + nwaves < nrows; row += 2 * nwaves) {
        int rowB = row + nwaves;
        int iA = (row  << 6) | lane;
        int iB = (rowB << 6) | lane;
        vfloat4 vA = __builtin_nontemporal_load(&x4[iA]);
        vfloat4 vB = __builtin_nontemporal_load(&x4[iB]);
        int mA = shift[row]  & 255;
        int mB = shift[rowB] & 255;
        vfloat4 oA = roll_row(vA, mA, lane);
        vfloat4 oB = roll_row(vB, mB, lane);
        __builtin_nontemporal_store(oA, &out4[iA]);
        __builtin_nontemporal_store(oB, &out4[iB]);
    }
    for (; row < nrows; row += nwaves) {
        int i = (row << 6) | lane;
        vfloat4 v = __builtin_nontemporal_load(&x4[i]);
        int m = shift[row] & 255;
        vfloat4 o = roll_row(v, m, lane);
        __builtin_nontemporal_store(o, &out4[i]);
    }
}

extern "C" void kernel_launch(void* const* d_in, const int* in_sizes, int n_in,
                              void* d_out, int out_size, void* d_ws, size_t ws_size,
                              hipStream_t stream)
{
    const vfloat4* x4    = (const vfloat4*)d_in[0];
    const int*     shift = (const int*)   d_in[1];
    vfloat4*       out4  = (vfloat4*)d_out;

    int nrows  = in_sizes[0] >> 8;   // 100,352 rows of 256 channels
    int blocks = 2048;               // 8192 waves, ~12.25 rows/wave, grid-stride

    hipLaunchKernelGGL(ChannelRoll_kernel, dim3(blocks), dim3(256), 0, stream,
                       x4, shift, out4, nrows);
}

// Round 5
// 34.694 us; speedup vs baseline: 1.1365x; 1.1365x over previous
//
#include <hip/hip_runtime.h>

// ChannelRoll: out[row, c] = x[row, (c + m[row]) & 255], C = 256 fp32, rows = B*H*W.
// One wave = one row, one-shot launch (no grid-stride): maximal TLP is what
// saturates HBM here (R4 post-mortem: grid-stride + nontemporal regressed 13%).
// Coalesced float4 read AND write; the circular roll is done in-register:
// m = 4q + r (wave-uniform), output slot j comes from source slot s=(j+r)&3 of
// lane (lane + q + (s<r)) & 63 -> 4 shuffles + uniform slot rotation.

__global__ __launch_bounds__(256) void ChannelRoll_kernel(
    const float4* __restrict__ x4,
    const int*    __restrict__ shift,
    float4*       __restrict__ out4,
    int total4)
{
    int gid = blockIdx.x * blockDim.x + threadIdx.x;
    if (gid >= total4) return;

    int row  = gid >> 6;         // 64 float4 per 256-channel row
    int lane = threadIdx.x & 63; // wave-local lane == position within row

    float4 v = x4[gid];          // lane holds dwords 4*lane .. 4*lane+3 (coalesced)

    int m = shift[row] & 255;    // wave-uniform
    int q = m >> 2;
    int r = m & 3;

    // Slot s of the rotated row lives at lane (lane + q + (s < r)) & 63.
    float t0 = __shfl(v.x, (lane + q + (0 < r ? 1 : 0)) & 63, 64);
    float t1 = __shfl(v.y, (lane + q + (1 < r ? 1 : 0)) & 63, 64);
    float t2 = __shfl(v.z, (lane + q + (2 < r ? 1 : 0)) & 63, 64);
    float t3 = __shfl(v.w, (lane + q + (3 < r ? 1 : 0)) & 63, 64);

    // out slot j = t[(j + r) & 3]  (r wave-uniform -> uniform branch)
    float4 o;
    switch (r) {
        case 0:  o = make_float4(t0, t1, t2, t3); break;
        case 1:  o = make_float4(t1, t2, t3, t0); break;
        case 2:  o = make_float4(t2, t3, t0, t1); break;
        default: o = make_float4(t3, t0, t1, t2); break;
    }

    out4[gid] = o;               // coalesced
}

extern "C" void kernel_launch(void* const* d_in, const int* in_sizes, int n_in,
                              void* d_out, int out_size, void* d_ws, size_t ws_size,
                              hipStream_t stream)
{
    const float4* x4    = (const float4*)d_in[0];
    const int*    shift = (const int*)  d_in[1];
    float4*       out4  = (float4*)d_out;

    int total4 = in_sizes[0] >> 2;            // 6,422,528 (exact multiple of 256)
    int blocks = (total4 + 255) / 256;        // 25,088

    hipLaunchKernelGGL(ChannelRoll_kernel, dim3(blocks), dim3(256), 0, stream,
                       x4, shift, out4, total4);
}